// Round 2
// baseline (590.006 us; speedup 1.0000x reference)
//
#include <hip/hip_runtime.h>
#include <hip/hip_bf16.h>

#define DEVI __device__ __forceinline__

typedef __attribute__((ext_vector_type(4))) float f32x4;
typedef __attribute__((ext_vector_type(8))) short bf16x8;

constexpr int Bb = 4, Tt = 2048, Cc = 1024, Hh = 16, HDd = 64;
constexpr int Mm = Bb * Tt; // 8192

// ---- bf16 helpers ----
DEVI short f2bf(float f) {
    union { float f; unsigned u; } x; x.f = f;
    unsigned r = x.u + 0x7FFFu + ((x.u >> 16) & 1u); // round-nearest-even
    return (short)(r >> 16);
}

DEVI void gload_lds16(const void* g, void* l) {
    __builtin_amdgcn_global_load_lds(
        (const __attribute__((address_space(1))) unsigned int*)g,
        (__attribute__((address_space(3))) unsigned int*)l, 16, 0, 0);
}

// ---------------- fp32 -> bf16 conversion ----------------
__global__ void cvt_kernel(const float* __restrict__ s, short* __restrict__ d, int n8) {
    int i = blockIdx.x * 256 + threadIdx.x;
    if (i < n8) {
        const float4* sp = (const float4*)s;
        float4 a = sp[2 * i], b = sp[2 * i + 1];
        short tmp[8];
        tmp[0] = f2bf(a.x); tmp[1] = f2bf(a.y); tmp[2] = f2bf(a.z); tmp[3] = f2bf(a.w);
        tmp[4] = f2bf(b.x); tmp[5] = f2bf(b.y); tmp[6] = f2bf(b.z); tmp[7] = f2bf(b.w);
        *(bf16x8*)(d + 8 * (size_t)i) = *(bf16x8*)tmp;
    }
}

// ---------------- GEMM: C[M][N] = A[M][K] * Bw[N][K]^T + bias ----------------
template<typename OutT> DEVI OutT cvt_out(float v);
template<> DEVI float cvt_out<float>(float v) { return v; }
template<> DEVI short cvt_out<short>(float v) { return f2bf(v); }

template<typename OutT>
__global__ __launch_bounds__(256, 2)
void gemm_bt(const short* __restrict__ A, const short* __restrict__ Bw,
             const float* __restrict__ bias, OutT* __restrict__ Cout,
             int Mdim, int Ndim, int Kdim)
{
    constexpr int BM = 128, BN = 128, BK = 64;
    __shared__ __align__(16) short As[BM][BK];
    __shared__ __align__(16) short Bs[BN][BK];
    const int bm = blockIdx.x * BM;
    const int bn = blockIdx.y * BN;
    const int tid = threadIdx.x;
    const int lane = tid & 63, wid = tid >> 6;
    const int wr = wid >> 1, wc = wid & 1; // 2x2 waves -> 64x64 each

    f32x4 acc[4][4] = {};

    const int lrow = lane >> 3;        // row within 8-row chunk
    const int lcol = (lane & 7) * 8;   // bf16 column offset (16B per lane)

    for (int k0 = 0; k0 < Kdim; k0 += BK) {
        #pragma unroll
        for (int c = 0; c < 4; ++c) {
            const int chunk = wid * 4 + c;        // 0..15, 8 rows each
            const int row = chunk * 8 + lrow;
            gload_lds16(A  + (size_t)(bm + row) * Kdim + k0 + lcol, &As[chunk * 8][0]);
            gload_lds16(Bw + (size_t)(bn + row) * Kdim + k0 + lcol, &Bs[chunk * 8][0]);
        }
        __syncthreads();
        const int rr = lane & 15;
        #pragma unroll
        for (int kk = 0; kk < BK; kk += 32) {
            const int koff = kk + (lane >> 4) * 8;
            bf16x8 af[4], bfr[4];
            #pragma unroll
            for (int m_ = 0; m_ < 4; ++m_)
                af[m_] = *(const bf16x8*)&As[wr * 64 + m_ * 16 + rr][koff];
            #pragma unroll
            for (int n_ = 0; n_ < 4; ++n_)
                bfr[n_] = *(const bf16x8*)&Bs[wc * 64 + n_ * 16 + rr][koff];
            #pragma unroll
            for (int m_ = 0; m_ < 4; ++m_)
                #pragma unroll
                for (int n_ = 0; n_ < 4; ++n_)
                    acc[m_][n_] = __builtin_amdgcn_mfma_f32_16x16x32_bf16(
                        af[m_], bfr[n_], acc[m_][n_], 0, 0, 0);
        }
        __syncthreads();
    }

    const int cidx = lane & 15;
    const int r4 = (lane >> 4) * 4;
    #pragma unroll
    for (int n_ = 0; n_ < 4; ++n_) {
        const int col = bn + wc * 64 + n_ * 16 + cidx;
        const float bv = bias[col];
        #pragma unroll
        for (int m_ = 0; m_ < 4; ++m_) {
            const int rowb = bm + wr * 64 + m_ * 16 + r4;
            #pragma unroll
            for (int i = 0; i < 4; ++i)
                Cout[(size_t)(rowb + i) * Ndim + col] = cvt_out<OutT>(acc[m_][n_][i] + bv);
        }
    }
}

// ---------------- V transpose: Vt[bh][d][t] = V[b*T+t][h*64+d] ----------------
__global__ __launch_bounds__(256, 4)
void vtrans_kernel(const short* __restrict__ V, short* __restrict__ Vt)
{
    const int tt = blockIdx.x, bh = blockIdx.y;
    const int b = bh >> 4, h = bh & 15;
    const int t0 = tt * 64;
    __shared__ __align__(16) short tile[64][72];
    const int tid = threadIdx.x;
    #pragma unroll
    for (int p = 0; p < 2; ++p) {
        const int c = tid + p * 256;
        const int r = c >> 3, cc = c & 7;       // r = t index, cc = d-chunk
        bf16x8 v = *(const bf16x8*)(V + ((size_t)(b * Tt + t0 + r)) * Cc + h * HDd + cc * 8);
        const int ccs = cc ^ ((r >> 3) & 7);    // XOR block-swizzle keeps 16B chunks intact
        *(bf16x8*)&tile[r][ccs * 8] = v;
    }
    __syncthreads();
    #pragma unroll
    for (int p = 0; p < 2; ++p) {
        const int c = tid + p * 256;
        const int d = c >> 3, tc = c & 7;
        short tmp[8];
        #pragma unroll
        for (int j = 0; j < 8; ++j) {
            const int t = tc * 8 + j;
            const int col = d ^ (8 * ((t >> 3) & 7));
            tmp[j] = tile[t][col];
        }
        *(bf16x8*)(Vt + ((size_t)bh * HDd + d) * Tt + t0 + tc * 8) = *(bf16x8*)tmp;
    }
}

// ---------------- Flash attention (causal, barrier-free) ----------------
// grid: (T/64 reversed, B*H); block 256 = 4 independent waves, each owns 16 q-rows.
// K read direct from global (row-major); V read direct from pre-transposed Vt.
template<bool DIAG>
DEVI void attn_tile(int kv0, const short* kbase, const short* vbase,
                    bf16x8 qf0, bf16x8 qf1, int lane, short (*PsW)[72],
                    f32x4 (&oacc)[4], float (&mrow)[4], float (&lsum)[4], int myq)
{
    const int rr = lane & 15;
    const int koff = (lane >> 4) * 8;
    const float SCL = 0.125f * 1.44269504088896f; // 1/sqrt(64) * log2(e)

    f32x4 sacc[4] = {};
    #pragma unroll
    for (int n = 0; n < 4; ++n) {
        const short* kr = kbase + (size_t)(kv0 + n * 16 + rr) * Cc + koff;
        bf16x8 kf0 = *(const bf16x8*)kr;
        bf16x8 kf1 = *(const bf16x8*)(kr + 32);
        sacc[n] = __builtin_amdgcn_mfma_f32_16x16x32_bf16(qf0, kf0, sacc[n], 0, 0, 0);
        sacc[n] = __builtin_amdgcn_mfma_f32_16x16x32_bf16(qf1, kf1, sacc[n], 0, 0, 0);
    }

    float p[4][4], tmax[4];
    #pragma unroll
    for (int i = 0; i < 4; ++i) {
        float mx = -3.0e38f;
        #pragma unroll
        for (int n = 0; n < 4; ++n) {
            float s = sacc[n][i] * SCL;
            if (DIAG) { if (kv0 + n * 16 + rr > myq + i) s = -3.0e38f; }
            p[n][i] = s;
            mx = fmaxf(mx, s);
        }
        tmax[i] = mx;
    }
    #pragma unroll
    for (int d = 1; d < 16; d <<= 1)
        #pragma unroll
        for (int i = 0; i < 4; ++i)
            tmax[i] = fmaxf(tmax[i], __shfl_xor(tmax[i], d, 64));
    #pragma unroll
    for (int i = 0; i < 4; ++i) {
        const float mnew = fmaxf(mrow[i], tmax[i]);
        const float alpha = exp2f(mrow[i] - mnew);
        mrow[i] = mnew;
        float rs = 0.f;
        #pragma unroll
        for (int n = 0; n < 4; ++n) {
            const float pe = exp2f(p[n][i] - mnew);
            p[n][i] = pe;
            rs += pe;
        }
        lsum[i] = lsum[i] * alpha + rs;   // per-lane partial; reduced in epilogue
        #pragma unroll
        for (int n = 0; n < 4; ++n) oacc[n][i] *= alpha;
    }
    #pragma unroll
    for (int i = 0; i < 4; ++i)
        #pragma unroll
        for (int n = 0; n < 4; ++n)
            PsW[(lane >> 4) * 4 + i][n * 16 + rr] = f2bf(p[n][i]);

    #pragma unroll
    for (int n = 0; n < 4; ++n) {
        #pragma unroll
        for (int ks = 0; ks < 2; ++ks) {
            bf16x8 pf = *(const bf16x8*)&PsW[rr][ks * 32 + koff];
            const short* vr = vbase + (size_t)(n * 16 + rr) * Tt + kv0 + ks * 32 + koff;
            bf16x8 vf = *(const bf16x8*)vr;
            oacc[n] = __builtin_amdgcn_mfma_f32_16x16x32_bf16(pf, vf, oacc[n], 0, 0, 0);
        }
    }
}

__global__ __launch_bounds__(256, 4)
void attn_kernel(const short* __restrict__ Q, const short* __restrict__ K,
                 const short* __restrict__ Vt, short* __restrict__ O)
{
    const int qt = gridDim.x - 1 - blockIdx.x;   // longest blocks dispatched first
    const int bh = blockIdx.y;
    const int b = bh >> 4, h = bh & 15;
    const size_t baseRow = (size_t)b * Tt;
    const int q0 = qt * 64;
    const int tid = threadIdx.x, lane = tid & 63, wid = tid >> 6;
    const int rr = lane & 15;
    const int koff = (lane >> 4) * 8;

    __shared__ __align__(16) short Ps[4][16][72];
    short (*PsW)[72] = Ps[wid];

    const int qrow = q0 + wid * 16 + rr;
    const short* qptr = Q + (baseRow + qrow) * Cc + h * HDd + koff;
    bf16x8 qf0 = *(const bf16x8*)qptr;
    bf16x8 qf1 = *(const bf16x8*)(qptr + 32);

    const short* kbase = K + baseRow * Cc + h * HDd;
    const short* vbase = Vt + (size_t)bh * HDd * Tt;

    f32x4 oacc[4] = {};
    float mrow[4], lsum[4];
    #pragma unroll
    for (int i = 0; i < 4; ++i) { mrow[i] = -3.0e38f; lsum[i] = 0.f; }

    const int myq = q0 + wid * 16 + (lane >> 4) * 4;

    for (int kt = 0; kt < qt; ++kt)
        attn_tile<false>(kt * 64, kbase, vbase, qf0, qf1, lane, PsW, oacc, mrow, lsum, myq);
    attn_tile<true>(qt * 64, kbase, vbase, qf0, qf1, lane, PsW, oacc, mrow, lsum, myq);

    // epilogue: reduce per-lane partial l across the 16-lane group, then store
    #pragma unroll
    for (int d = 1; d < 16; d <<= 1)
        #pragma unroll
        for (int i = 0; i < 4; ++i)
            lsum[i] += __shfl_xor(lsum[i], d, 64);

    #pragma unroll
    for (int n = 0; n < 4; ++n)
        #pragma unroll
        for (int i = 0; i < 4; ++i) {
            const float v = oacc[n][i] / lsum[i];
            O[(baseRow + q0 + wid * 16 + (lane >> 4) * 4 + i) * Cc + h * HDd + n * 16 + rr] = f2bf(v);
        }
}

// ---------------- host ----------------
extern "C" void kernel_launch(void* const* d_in, const int* in_sizes, int n_in,
                              void* d_out, int out_size, void* d_ws, size_t ws_size,
                              hipStream_t stream) {
    (void)in_sizes; (void)n_in; (void)out_size; (void)ws_size;
    const float* x  = (const float*)d_in[0];
    const float* Wq = (const float*)d_in[1];
    const float* bq = (const float*)d_in[2];
    const float* Wk = (const float*)d_in[3];
    const float* bk = (const float*)d_in[4];
    const float* Wv = (const float*)d_in[5];
    const float* bv = (const float*)d_in[6];
    const float* Wo = (const float*)d_in[7];
    const float* bo = (const float*)d_in[8];
    float* out = (float*)d_out;

    short* ws  = (short*)d_ws;
    short* xb  = ws;
    short* wqb = xb  + (size_t)Mm * Cc;
    short* wkb = wqb + (size_t)Cc * Cc;
    short* wvb = wkb + (size_t)Cc * Cc;
    short* wob = wvb + (size_t)Cc * Cc;
    short* Qb  = wob + (size_t)Cc * Cc;
    short* Kb  = Qb  + (size_t)Mm * Cc;
    short* Vb  = Kb  + (size_t)Mm * Cc;
    short* Ob  = Vb  + (size_t)Mm * Cc;
    short* vtb = xb;  // xb is dead after the V projection; reuse for transposed V

    const int nx8 = Mm * Cc / 8;
    const int nw8 = Cc * Cc / 8;
    cvt_kernel<<<(nx8 + 255) / 256, 256, 0, stream>>>(x,  xb,  nx8);
    cvt_kernel<<<(nw8 + 255) / 256, 256, 0, stream>>>(Wq, wqb, nw8);
    cvt_kernel<<<(nw8 + 255) / 256, 256, 0, stream>>>(Wk, wkb, nw8);
    cvt_kernel<<<(nw8 + 255) / 256, 256, 0, stream>>>(Wv, wvb, nw8);
    cvt_kernel<<<(nw8 + 255) / 256, 256, 0, stream>>>(Wo, wob, nw8);

    dim3 g(Mm / 128, Cc / 128);
    gemm_bt<short><<<g, 256, 0, stream>>>(xb, wqb, bq, Qb, Mm, Cc, Cc);
    gemm_bt<short><<<g, 256, 0, stream>>>(xb, wkb, bk, Kb, Mm, Cc, Cc);
    gemm_bt<short><<<g, 256, 0, stream>>>(xb, wvb, bv, Vb, Mm, Cc, Cc);

    vtrans_kernel<<<dim3(Tt / 64, Bb * Hh), 256, 0, stream>>>(Vb, vtb);

    attn_kernel<<<dim3(Tt / 64, Bb * Hh), 256, 0, stream>>>(Qb, Kb, vtb, Ob);

    gemm_bt<float><<<g, 256, 0, stream>>>(Ob, wob, bo, out, Mm, Cc, Cc);
}

// Round 3
// 329.955 us; speedup vs baseline: 1.7881x; 1.7881x over previous
//
#include <hip/hip_runtime.h>
#include <hip/hip_bf16.h>

#define DEVI __device__ __forceinline__

typedef __attribute__((ext_vector_type(4))) float f32x4;
typedef __attribute__((ext_vector_type(8))) short bf16x8;
typedef __attribute__((ext_vector_type(4))) short bf16x4;

constexpr int Bb = 4, Tt = 2048, Cc = 1024, Hh = 16, HDd = 64;
constexpr int Mm = Bb * Tt; // 8192

// ---- bf16 helpers ----
DEVI short f2bf(float f) {
    union { float f; unsigned u; } x; x.f = f;
    unsigned r = x.u + 0x7FFFu + ((x.u >> 16) & 1u); // round-nearest-even
    return (short)(r >> 16);
}

DEVI void gload_lds16(const void* g, void* l) {
    __builtin_amdgcn_global_load_lds(
        (const __attribute__((address_space(1))) unsigned int*)g,
        (__attribute__((address_space(3))) unsigned int*)l, 16, 0, 0);
}

// ---------------- fp32 -> bf16 conversion ----------------
__global__ void cvt_kernel(const float* __restrict__ s, short* __restrict__ d, int n8) {
    int i = blockIdx.x * 256 + threadIdx.x;
    if (i < n8) {
        const float4* sp = (const float4*)s;
        float4 a = sp[2 * i], b = sp[2 * i + 1];
        short tmp[8];
        tmp[0] = f2bf(a.x); tmp[1] = f2bf(a.y); tmp[2] = f2bf(a.z); tmp[3] = f2bf(a.w);
        tmp[4] = f2bf(b.x); tmp[5] = f2bf(b.y); tmp[6] = f2bf(b.z); tmp[7] = f2bf(b.w);
        *(bf16x8*)(d + 8 * (size_t)i) = *(bf16x8*)tmp;
    }
}

// ---------------- GEMM: C[M][N] = A[M][K] * Bw[N][K]^T + bias ----------------
// MODE 0: fp32 row-major out. MODE 1: bf16 row-major out.
// MODE 2: bf16 out written as Vt[bh][d][t] (transposed for attention's PV).
template<int MODE>
__global__ __launch_bounds__(256, 2)
void gemm_bt(const short* __restrict__ A, const short* __restrict__ Bw,
             const float* __restrict__ bias, void* __restrict__ outp,
             int Mdim, int Ndim, int Kdim)
{
    constexpr int BM = 128, BN = 128, BK = 64;
    __shared__ __align__(16) short As[BM][BK];
    __shared__ __align__(16) short Bs[BN][BK];
    const int bm = blockIdx.x * BM;
    const int bn = blockIdx.y * BN;
    const int tid = threadIdx.x;
    const int lane = tid & 63, wid = tid >> 6;
    const int wr = wid >> 1, wc = wid & 1; // 2x2 waves -> 64x64 each

    f32x4 acc[4][4] = {};

    const int lrow = lane >> 3;
    const int lcol = (lane & 7) * 8;

    for (int k0 = 0; k0 < Kdim; k0 += BK) {
        #pragma unroll
        for (int c = 0; c < 4; ++c) {
            const int chunk = wid * 4 + c;
            const int row = chunk * 8 + lrow;
            gload_lds16(A  + (size_t)(bm + row) * Kdim + k0 + lcol, &As[chunk * 8][0]);
            gload_lds16(Bw + (size_t)(bn + row) * Kdim + k0 + lcol, &Bs[chunk * 8][0]);
        }
        __syncthreads();
        const int rr = lane & 15;
        #pragma unroll
        for (int kk = 0; kk < BK; kk += 32) {
            const int koff = kk + (lane >> 4) * 8;
            bf16x8 af[4], bfr[4];
            #pragma unroll
            for (int m_ = 0; m_ < 4; ++m_)
                af[m_] = *(const bf16x8*)&As[wr * 64 + m_ * 16 + rr][koff];
            #pragma unroll
            for (int n_ = 0; n_ < 4; ++n_)
                bfr[n_] = *(const bf16x8*)&Bs[wc * 64 + n_ * 16 + rr][koff];
            #pragma unroll
            for (int m_ = 0; m_ < 4; ++m_)
                #pragma unroll
                for (int n_ = 0; n_ < 4; ++n_)
                    acc[m_][n_] = __builtin_amdgcn_mfma_f32_16x16x32_bf16(
                        af[m_], bfr[n_], acc[m_][n_], 0, 0, 0);
        }
        __syncthreads();
    }

    const int cidx = lane & 15;
    const int r4 = (lane >> 4) * 4;
    #pragma unroll
    for (int n_ = 0; n_ < 4; ++n_) {
        const int col = bn + wc * 64 + n_ * 16 + cidx;
        const float bv = bias[col];
        #pragma unroll
        for (int m_ = 0; m_ < 4; ++m_) {
            const int rowb = bm + wr * 64 + m_ * 16 + r4;
            if constexpr (MODE == 0) {
                float* C = (float*)outp;
                #pragma unroll
                for (int i = 0; i < 4; ++i)
                    C[(size_t)(rowb + i) * Ndim + col] = acc[m_][n_][i] + bv;
            } else if constexpr (MODE == 1) {
                short* C = (short*)outp;
                #pragma unroll
                for (int i = 0; i < 4; ++i)
                    C[(size_t)(rowb + i) * Ndim + col] = f2bf(acc[m_][n_][i] + bv);
            } else {
                // transposed V: Vt[((b*16+h)*64 + d)][t], 4 consecutive t -> packed 8B
                short* C = (short*)outp;
                const int h_ = col >> 6, d_ = col & 63;
                const int b_ = rowb >> 11, t_ = rowb & 2047;
                short tmp[4];
                #pragma unroll
                for (int i = 0; i < 4; ++i) tmp[i] = f2bf(acc[m_][n_][i] + bv);
                *(bf16x4*)(C + ((size_t)((b_ * Hh + h_) * HDd + d_)) * Tt + t_) = *(bf16x4*)tmp;
            }
        }
    }
}

// ---------------- Flash attention (causal, staged + double-buffered) ----------------
// grid: (T/64 reversed, B*H); block 256 = 4 waves, each owns 16 q-rows.
// K staged to LDS [64][64] via global_load_lds with source-side XOR chunk swizzle;
// V staged from pre-transposed Vt the same way. Reads apply the same swizzle.
template<bool DIAG>
DEVI void attn_tile(int kv0, const short (*Kt)[64], const short (*Vd)[64],
                    bf16x8 qf0, bf16x8 qf1, int lane, short (*PsW)[72],
                    f32x4 (&oacc)[4], float (&mrow)[4], float (&lsum)[4], int myq)
{
    const int rr = lane & 15;
    const int g  = lane >> 4;
    const float SCL = 0.125f * 1.44269504088896f; // 1/sqrt(64) * log2(e)

    f32x4 sacc[4] = {};
    #pragma unroll
    for (int n = 0; n < 4; ++n) {
        const int row = n * 16 + rr;
        const int sw = row & 7;
        bf16x8 kf0 = *(const bf16x8*)&Kt[row][((g    ) ^ sw) * 8];
        bf16x8 kf1 = *(const bf16x8*)&Kt[row][((g + 4) ^ sw) * 8];
        sacc[n] = __builtin_amdgcn_mfma_f32_16x16x32_bf16(qf0, kf0, sacc[n], 0, 0, 0);
        sacc[n] = __builtin_amdgcn_mfma_f32_16x16x32_bf16(qf1, kf1, sacc[n], 0, 0, 0);
    }

    float p[4][4], tmax[4];
    #pragma unroll
    for (int i = 0; i < 4; ++i) {
        float mx = -3.0e38f;
        #pragma unroll
        for (int n = 0; n < 4; ++n) {
            float s = sacc[n][i] * SCL;
            if (DIAG) { if (kv0 + n * 16 + rr > myq + i) s = -3.0e38f; }
            p[n][i] = s;
            mx = fmaxf(mx, s);
        }
        tmax[i] = mx;
    }
    #pragma unroll
    for (int d = 1; d < 16; d <<= 1)
        #pragma unroll
        for (int i = 0; i < 4; ++i)
            tmax[i] = fmaxf(tmax[i], __shfl_xor(tmax[i], d, 64));
    #pragma unroll
    for (int i = 0; i < 4; ++i) {
        const float mnew = fmaxf(mrow[i], tmax[i]);
        const float alpha = exp2f(mrow[i] - mnew);
        mrow[i] = mnew;
        float rs = 0.f;
        #pragma unroll
        for (int n = 0; n < 4; ++n) {
            const float pe = exp2f(p[n][i] - mnew);
            p[n][i] = pe;
            rs += pe;
        }
        lsum[i] = lsum[i] * alpha + rs;   // per-lane partial; reduced in epilogue
        #pragma unroll
        for (int n = 0; n < 4; ++n) oacc[n][i] *= alpha;
    }
    #pragma unroll
    for (int i = 0; i < 4; ++i)
        #pragma unroll
        for (int n = 0; n < 4; ++n)
            PsW[g * 4 + i][n * 16 + rr] = f2bf(p[n][i]);

    #pragma unroll
    for (int n = 0; n < 4; ++n) {
        const int row = n * 16 + rr;
        const int sw = row & 7;
        #pragma unroll
        for (int ks = 0; ks < 2; ++ks) {
            bf16x8 pf = *(const bf16x8*)&PsW[rr][ks * 32 + g * 8];
            bf16x8 vf = *(const bf16x8*)&Vd[row][(((ks ? g + 4 : g)) ^ sw) * 8];
            oacc[n] = __builtin_amdgcn_mfma_f32_16x16x32_bf16(pf, vf, oacc[n], 0, 0, 0);
        }
    }
}

__global__ __launch_bounds__(256, 3)
void attn_kernel(const short* __restrict__ Q, const short* __restrict__ K,
                 const short* __restrict__ Vt, short* __restrict__ O)
{
    const int qt = gridDim.x - 1 - blockIdx.x;   // longest blocks first
    const int bh = blockIdx.y;
    const int b = bh >> 4, h = bh & 15;
    const size_t baseRow = (size_t)b * Tt;
    const int q0 = qt * 64;
    const int tid = threadIdx.x, lane = tid & 63, wid = tid >> 6;
    const int rr = lane & 15;
    const int g = lane >> 4;

    __shared__ __align__(16) short Kb[2][64][64];
    __shared__ __align__(16) short Vb[2][64][64];
    __shared__ __align__(16) short Ps[4][16][72];
    short (*PsW)[72] = Ps[wid];

    const int qrow = q0 + wid * 16 + rr;
    const short* qptr = Q + (baseRow + qrow) * Cc + h * HDd + g * 8;
    bf16x8 qf0 = *(const bf16x8*)qptr;
    bf16x8 qf1 = *(const bf16x8*)(qptr + 32);

    const short* kbase = K + baseRow * Cc + h * HDd;
    const short* vbase = Vt + (size_t)bh * HDd * Tt;

    f32x4 oacc[4] = {};
    float mrow[4], lsum[4];
    #pragma unroll
    for (int i = 0; i < 4; ++i) { mrow[i] = -3.0e38f; lsum[i] = 0.f; }

    const int myq = q0 + wid * 16 + g * 4;
    const int nkv = qt + 1;

    auto STAGE = [&](int bsel, int kv0) {
        #pragma unroll
        for (int j = 0; j < 2; ++j) {
            const int r0 = wid * 16 + j * 8;
            const int row = r0 + (lane >> 3);
            const int sc = ((lane & 7) ^ (row & 7)) * 8;   // source-side chunk swizzle
            gload_lds16(kbase + (size_t)(kv0 + row) * Cc + sc, &Kb[bsel][r0][0]);
            gload_lds16(vbase + (size_t)row * Tt + kv0 + sc, &Vb[bsel][r0][0]);
        }
    };

    STAGE(0, 0);
    __syncthreads();
    int buf = 0;
    for (int kt = 0; kt < nkv; ++kt) {
        if (kt + 1 < nkv) STAGE(buf ^ 1, (kt + 1) * 64);
        if (kt == nkv - 1)
            attn_tile<true >(kt * 64, Kb[buf], Vb[buf], qf0, qf1, lane, PsW, oacc, mrow, lsum, myq);
        else
            attn_tile<false>(kt * 64, Kb[buf], Vb[buf], qf0, qf1, lane, PsW, oacc, mrow, lsum, myq);
        __syncthreads();
        buf ^= 1;
    }

    // epilogue: reduce per-lane partial l across the 16-lane group, then store
    #pragma unroll
    for (int d = 1; d < 16; d <<= 1)
        #pragma unroll
        for (int i = 0; i < 4; ++i)
            lsum[i] += __shfl_xor(lsum[i], d, 64);

    #pragma unroll
    for (int n = 0; n < 4; ++n)
        #pragma unroll
        for (int i = 0; i < 4; ++i) {
            const float v = oacc[n][i] / lsum[i];
            O[(baseRow + q0 + wid * 16 + g * 4 + i) * Cc + h * HDd + n * 16 + rr] = f2bf(v);
        }
}

// ---------------- host ----------------
extern "C" void kernel_launch(void* const* d_in, const int* in_sizes, int n_in,
                              void* d_out, int out_size, void* d_ws, size_t ws_size,
                              hipStream_t stream) {
    (void)in_sizes; (void)n_in; (void)out_size; (void)ws_size;
    const float* x  = (const float*)d_in[0];
    const float* Wq = (const float*)d_in[1];
    const float* bq = (const float*)d_in[2];
    const float* Wk = (const float*)d_in[3];
    const float* bk = (const float*)d_in[4];
    const float* Wv = (const float*)d_in[5];
    const float* bv = (const float*)d_in[6];
    const float* Wo = (const float*)d_in[7];
    const float* bo = (const float*)d_in[8];
    float* out = (float*)d_out;

    short* ws  = (short*)d_ws;
    short* xb  = ws;
    short* wqb = xb  + (size_t)Mm * Cc;
    short* wkb = wqb + (size_t)Cc * Cc;
    short* wvb = wkb + (size_t)Cc * Cc;
    short* wob = wvb + (size_t)Cc * Cc;
    short* Qb  = wob + (size_t)Cc * Cc;
    short* Kbg = Qb  + (size_t)Mm * Cc;
    short* Vtb = Kbg + (size_t)Mm * Cc;  // V written pre-transposed by the V-proj GEMM
    short* Ob  = Vtb + (size_t)Mm * Cc;

    const int nx8 = Mm * Cc / 8;
    const int nw8 = Cc * Cc / 8;
    cvt_kernel<<<(nx8 + 255) / 256, 256, 0, stream>>>(x,  xb,  nx8);
    cvt_kernel<<<(nw8 + 255) / 256, 256, 0, stream>>>(Wq, wqb, nw8);
    cvt_kernel<<<(nw8 + 255) / 256, 256, 0, stream>>>(Wk, wkb, nw8);
    cvt_kernel<<<(nw8 + 255) / 256, 256, 0, stream>>>(Wv, wvb, nw8);
    cvt_kernel<<<(nw8 + 255) / 256, 256, 0, stream>>>(Wo, wob, nw8);

    dim3 g(Mm / 128, Cc / 128);
    gemm_bt<1><<<g, 256, 0, stream>>>(xb, wqb, bq, Qb,  Mm, Cc, Cc);
    gemm_bt<1><<<g, 256, 0, stream>>>(xb, wkb, bk, Kbg, Mm, Cc, Cc);
    gemm_bt<2><<<g, 256, 0, stream>>>(xb, wvb, bv, Vtb, Mm, Cc, Cc);

    attn_kernel<<<dim3(Tt / 64, Bb * Hh), 256, 0, stream>>>(Qb, Kbg, Vtb, Ob);

    gemm_bt<0><<<g, 256, 0, stream>>>(Ob, wob, bo, out, Mm, Cc, Cc);
}

// Round 4
// 259.411 us; speedup vs baseline: 2.2744x; 1.2719x over previous
//
#include <hip/hip_runtime.h>
#include <hip/hip_bf16.h>

#define DEVI __device__ __forceinline__

typedef __attribute__((ext_vector_type(4))) float f32x4;
typedef __attribute__((ext_vector_type(8))) short bf16x8;
typedef __attribute__((ext_vector_type(4))) short bf16x4;

constexpr int Bb = 4, Tt = 2048, Cc = 1024, Hh = 16, HDd = 64;
constexpr int Mm = Bb * Tt; // 8192

// ---- bf16 helpers ----
DEVI short f2bf(float f) {
    union { float f; unsigned u; } x; x.f = f;
    unsigned r = x.u + 0x7FFFu + ((x.u >> 16) & 1u); // round-nearest-even
    return (short)(r >> 16);
}

DEVI int cvtpk(float lo, float hi) { // packs {bf16(lo), bf16(hi)}, lo in low 16
    int r;
    asm("v_cvt_pk_bf16_f32 %0, %1, %2" : "=v"(r) : "v"(lo), "v"(hi));
    return r;
}

DEVI void gload_lds16(const void* g, void* l) {
    __builtin_amdgcn_global_load_lds(
        (const __attribute__((address_space(1))) unsigned int*)g,
        (__attribute__((address_space(3))) unsigned int*)l, 16, 0, 0);
}

// ---------------- fp32 -> bf16 conversion ----------------
__global__ void cvt_kernel(const float* __restrict__ s, short* __restrict__ d, int n8) {
    int i = blockIdx.x * 256 + threadIdx.x;
    if (i < n8) {
        const float4* sp = (const float4*)s;
        float4 a = sp[2 * i], b = sp[2 * i + 1];
        short tmp[8];
        tmp[0] = f2bf(a.x); tmp[1] = f2bf(a.y); tmp[2] = f2bf(a.z); tmp[3] = f2bf(a.w);
        tmp[4] = f2bf(b.x); tmp[5] = f2bf(b.y); tmp[6] = f2bf(b.z); tmp[7] = f2bf(b.w);
        *(bf16x8*)(d + 8 * (size_t)i) = *(bf16x8*)tmp;
    }
}

// ---------------- GEMM: C[M][N] = (A[M][K] * Bw[N][K]^T + bias) * scale ----------------
// MODE 0: fp32 row-major out. MODE 1: bf16 row-major out.
// MODE 2: bf16 out written as Vt[bh][d][t] (transposed for attention's PV).
template<int MODE>
__global__ __launch_bounds__(256, 2)
void gemm_bt(const short* __restrict__ A, const short* __restrict__ Bw,
             const float* __restrict__ bias, void* __restrict__ outp,
             int Mdim, int Ndim, int Kdim, float scale)
{
    constexpr int BM = 128, BN = 128, BK = 64;
    __shared__ __align__(16) short As[BM][BK];
    __shared__ __align__(16) short Bs[BN][BK];
    const int bm = blockIdx.x * BM;
    const int bn = blockIdx.y * BN;
    const int tid = threadIdx.x;
    const int lane = tid & 63, wid = tid >> 6;
    const int wr = wid >> 1, wc = wid & 1; // 2x2 waves -> 64x64 each

    f32x4 acc[4][4] = {};

    const int lrow = lane >> 3;
    const int lcol = (lane & 7) * 8;

    for (int k0 = 0; k0 < Kdim; k0 += BK) {
        #pragma unroll
        for (int c = 0; c < 4; ++c) {
            const int chunk = wid * 4 + c;
            const int row = chunk * 8 + lrow;
            gload_lds16(A  + (size_t)(bm + row) * Kdim + k0 + lcol, &As[chunk * 8][0]);
            gload_lds16(Bw + (size_t)(bn + row) * Kdim + k0 + lcol, &Bs[chunk * 8][0]);
        }
        __syncthreads();
        const int rr = lane & 15;
        #pragma unroll
        for (int kk = 0; kk < BK; kk += 32) {
            const int koff = kk + (lane >> 4) * 8;
            bf16x8 af[4], bfr[4];
            #pragma unroll
            for (int m_ = 0; m_ < 4; ++m_)
                af[m_] = *(const bf16x8*)&As[wr * 64 + m_ * 16 + rr][koff];
            #pragma unroll
            for (int n_ = 0; n_ < 4; ++n_)
                bfr[n_] = *(const bf16x8*)&Bs[wc * 64 + n_ * 16 + rr][koff];
            #pragma unroll
            for (int m_ = 0; m_ < 4; ++m_)
                #pragma unroll
                for (int n_ = 0; n_ < 4; ++n_)
                    acc[m_][n_] = __builtin_amdgcn_mfma_f32_16x16x32_bf16(
                        af[m_], bfr[n_], acc[m_][n_], 0, 0, 0);
        }
        __syncthreads();
    }

    const int cidx = lane & 15;
    const int r4 = (lane >> 4) * 4;
    #pragma unroll
    for (int n_ = 0; n_ < 4; ++n_) {
        const int col = bn + wc * 64 + n_ * 16 + cidx;
        const float bv = bias[col];
        #pragma unroll
        for (int m_ = 0; m_ < 4; ++m_) {
            const int rowb = bm + wr * 64 + m_ * 16 + r4;
            if constexpr (MODE == 0) {
                float* C = (float*)outp;
                #pragma unroll
                for (int i = 0; i < 4; ++i)
                    C[(size_t)(rowb + i) * Ndim + col] = (acc[m_][n_][i] + bv) * scale;
            } else if constexpr (MODE == 1) {
                short* C = (short*)outp;
                #pragma unroll
                for (int i = 0; i < 4; ++i)
                    C[(size_t)(rowb + i) * Ndim + col] = f2bf((acc[m_][n_][i] + bv) * scale);
            } else {
                short* C = (short*)outp;
                const int h_ = col >> 6, d_ = col & 63;
                const int b_ = rowb >> 11, t_ = rowb & 2047;
                short tmp[4];
                #pragma unroll
                for (int i = 0; i < 4; ++i) tmp[i] = f2bf((acc[m_][n_][i] + bv) * scale);
                *(bf16x4*)(C + ((size_t)((b_ * Hh + h_) * HDd + d_)) * Tt + t_) = *(bf16x4*)tmp;
            }
        }
    }
}

// ---------------- Flash attention (causal, swapped-QK in-register softmax) ----------------
// grid: (T/64 reversed, B*H); block 256 = 4 waves, each owns 16 q-rows.
// Swapped QK: mfma(K,Q) -> lane holds S[kv = kv0+n*16+g*4+i][q = rr]; softmax is
// per-lane-scalar with a 2-step cross-group max reduce. P goes through a per-wave
// XOR-swizzled LDS tile (packed b64 writes, b128 reads) to form the PV A-fragment.
template<bool DIAG>
DEVI void attn_tile(int kv0, const short (*Kt)[64], const short (*Vd)[64],
                    bf16x8 qf0, bf16x8 qf1, int lane, short (*PsW)[64],
                    f32x4 (&oacc)[4], float &mrow, float &lsum, int qrow)
{
    const int rr = lane & 15;
    const int g  = lane >> 4;

    f32x4 sacc[4] = {};
    #pragma unroll
    for (int n = 0; n < 4; ++n) {
        const int row = n * 16 + rr;
        const int sw = row & 7;
        bf16x8 kf0 = *(const bf16x8*)&Kt[row][((g    ) ^ sw) * 8];
        bf16x8 kf1 = *(const bf16x8*)&Kt[row][((g + 4) ^ sw) * 8];
        sacc[n] = __builtin_amdgcn_mfma_f32_16x16x32_bf16(kf0, qf0, sacc[n], 0, 0, 0);
        sacc[n] = __builtin_amdgcn_mfma_f32_16x16x32_bf16(kf1, qf1, sacc[n], 0, 0, 0);
    }

    // lane holds S[kv0 + n*16 + g*4 + i][qrow]; scale already folded into Q
    float p[4][4];
    float pmax = -1e30f;
    #pragma unroll
    for (int n = 0; n < 4; ++n)
        #pragma unroll
        for (int i = 0; i < 4; ++i) {
            float s = sacc[n][i];
            if (DIAG) { if (kv0 + n * 16 + g * 4 + i > qrow) s = -1e30f; }
            p[n][i] = s;
            pmax = fmaxf(pmax, s);
        }
    pmax = fmaxf(pmax, __shfl_xor(pmax, 16, 64));
    pmax = fmaxf(pmax, __shfl_xor(pmax, 32, 64));

    if (!__all(pmax <= mrow + 8.0f)) {          // defer-max: rescale rarely
        const float mnew = fmaxf(mrow, pmax);
        const float alpha = exp2f(mrow - mnew);
        mrow = mnew;
        lsum *= alpha;
        float alphaq[4];
        #pragma unroll
        for (int i = 0; i < 4; ++i) alphaq[i] = __shfl(alpha, g * 4 + i, 16);
        #pragma unroll
        for (int n = 0; n < 4; ++n)
            #pragma unroll
            for (int i = 0; i < 4; ++i) oacc[n][i] *= alphaq[i];
    }

    // exp2, per-lane partial sum, pack to bf16, swizzled b64 stores to Ps[q][kv]
    #pragma unroll
    for (int n = 0; n < 4; ++n) {
        #pragma unroll
        for (int i = 0; i < 4; ++i) {
            p[n][i] = exp2f(p[n][i] - mrow);
            lsum += p[n][i];
        }
        const unsigned u0 = (unsigned)cvtpk(p[n][0], p[n][1]);
        const unsigned u1 = (unsigned)cvtpk(p[n][2], p[n][3]);
        const int chunk = (2 * n + (g >> 1)) ^ (rr & 7);
        *(unsigned long long*)&PsW[rr][chunk * 8 + (g & 1) * 4] =
            ((unsigned long long)u1 << 32) | u0;
    }

    // PV: pf = P[q=rr][ks*32 + g*8 .. +7] (same swizzle), vf from transposed V tile
    #pragma unroll
    for (int ks = 0; ks < 2; ++ks) {
        const int rchunk = (4 * ks + g) ^ (rr & 7);
        bf16x8 pf = *(const bf16x8*)&PsW[rr][rchunk * 8];
        #pragma unroll
        for (int n = 0; n < 4; ++n) {
            const int row = n * 16 + rr;
            const int sw = row & 7;
            bf16x8 vf = *(const bf16x8*)&Vd[row][((ks * 4 + g) ^ sw) * 8];
            oacc[n] = __builtin_amdgcn_mfma_f32_16x16x32_bf16(pf, vf, oacc[n], 0, 0, 0);
        }
    }
}

__global__ __launch_bounds__(256, 4)
void attn_kernel(const short* __restrict__ Q, const short* __restrict__ K,
                 const short* __restrict__ Vt, short* __restrict__ O)
{
    const int qt = gridDim.x - 1 - blockIdx.x;   // longest blocks first
    const int bh = blockIdx.y;
    const int b = bh >> 4, h = bh & 15;
    const size_t baseRow = (size_t)b * Tt;
    const int q0 = qt * 64;
    const int tid = threadIdx.x, lane = tid & 63, wid = tid >> 6;
    const int rr = lane & 15;
    const int g = lane >> 4;

    __shared__ __align__(16) short Kb[2][64][64];
    __shared__ __align__(16) short Vb[2][64][64];
    __shared__ __align__(16) short Ps[4][16][64];
    short (*PsW)[64] = Ps[wid];

    const int qrow = q0 + wid * 16 + rr;
    const short* qptr = Q + (baseRow + qrow) * Cc + h * HDd + g * 8;
    bf16x8 qf0 = *(const bf16x8*)qptr;
    bf16x8 qf1 = *(const bf16x8*)(qptr + 32);

    const short* kbase = K + baseRow * Cc + h * HDd;
    const short* vbase = Vt + (size_t)bh * HDd * Tt;

    f32x4 oacc[4] = {};
    float mrow = -1e30f, lsum = 0.f;
    const int nkv = qt + 1;

    auto STAGE = [&](int bsel, int kv0) {
        #pragma unroll
        for (int j = 0; j < 2; ++j) {
            const int r0 = wid * 16 + j * 8;
            const int row = r0 + (lane >> 3);
            const int sc = ((lane & 7) ^ (row & 7)) * 8;   // source-side chunk swizzle
            gload_lds16(kbase + (size_t)(kv0 + row) * Cc + sc, &Kb[bsel][r0][0]);
            gload_lds16(vbase + (size_t)row * Tt + kv0 + sc, &Vb[bsel][r0][0]);
        }
    };

    STAGE(0, 0);
    __syncthreads();
    int buf = 0;
    for (int kt = 0; kt < nkv; ++kt) {
        if (kt + 1 < nkv) STAGE(buf ^ 1, (kt + 1) * 64);
        if (kt == nkv - 1)
            attn_tile<true >(kt * 64, Kb[buf], Vb[buf], qf0, qf1, lane, PsW, oacc, mrow, lsum, qrow);
        else
            attn_tile<false>(kt * 64, Kb[buf], Vb[buf], qf0, qf1, lane, PsW, oacc, mrow, lsum, qrow);
        __syncthreads();
        buf ^= 1;
    }

    // epilogue: total l per q-row (2-step cross-group reduce), fetch per-output-row totals
    lsum += __shfl_xor(lsum, 16, 64);
    lsum += __shfl_xor(lsum, 32, 64);
    float rinv[4];
    #pragma unroll
    for (int i = 0; i < 4; ++i)
        rinv[i] = 1.0f / __shfl(lsum, g * 4 + i, 16);

    #pragma unroll
    for (int n = 0; n < 4; ++n)
        #pragma unroll
        for (int i = 0; i < 4; ++i)
            O[(baseRow + q0 + wid * 16 + g * 4 + i) * Cc + h * HDd + n * 16 + rr] =
                f2bf(oacc[n][i] * rinv[i]);
}

// ---------------- host ----------------
extern "C" void kernel_launch(void* const* d_in, const int* in_sizes, int n_in,
                              void* d_out, int out_size, void* d_ws, size_t ws_size,
                              hipStream_t stream) {
    (void)in_sizes; (void)n_in; (void)out_size; (void)ws_size;
    const float* x  = (const float*)d_in[0];
    const float* Wq = (const float*)d_in[1];
    const float* bq = (const float*)d_in[2];
    const float* Wk = (const float*)d_in[3];
    const float* bk = (const float*)d_in[4];
    const float* Wv = (const float*)d_in[5];
    const float* bv = (const float*)d_in[6];
    const float* Wo = (const float*)d_in[7];
    const float* bo = (const float*)d_in[8];
    float* out = (float*)d_out;

    short* ws  = (short*)d_ws;
    short* xb  = ws;
    short* wqb = xb  + (size_t)Mm * Cc;
    short* wkb = wqb + (size_t)Cc * Cc;
    short* wvb = wkb + (size_t)Cc * Cc;
    short* wob = wvb + (size_t)Cc * Cc;
    short* Qb  = wob + (size_t)Cc * Cc;
    short* Kbg = Qb  + (size_t)Mm * Cc;
    short* Vtb = Kbg + (size_t)Mm * Cc;  // V written pre-transposed by the V-proj GEMM
    short* Ob  = Vtb + (size_t)Mm * Cc;

    const int nx8 = Mm * Cc / 8;
    const int nw8 = Cc * Cc / 8;
    cvt_kernel<<<(nx8 + 255) / 256, 256, 0, stream>>>(x,  xb,  nx8);
    cvt_kernel<<<(nw8 + 255) / 256, 256, 0, stream>>>(Wq, wqb, nw8);
    cvt_kernel<<<(nw8 + 255) / 256, 256, 0, stream>>>(Wk, wkb, nw8);
    cvt_kernel<<<(nw8 + 255) / 256, 256, 0, stream>>>(Wv, wvb, nw8);
    cvt_kernel<<<(nw8 + 255) / 256, 256, 0, stream>>>(Wo, wob, nw8);

    const float SCL = 0.125f * 1.44269504088896f;  // 1/sqrt(HD) * log2(e), folded into Q
    dim3 g(Mm / 128, Cc / 128);
    gemm_bt<1><<<g, 256, 0, stream>>>(xb, wqb, bq, Qb,  Mm, Cc, Cc, SCL);
    gemm_bt<1><<<g, 256, 0, stream>>>(xb, wkb, bk, Kbg, Mm, Cc, Cc, 1.0f);
    gemm_bt<2><<<g, 256, 0, stream>>>(xb, wvb, bv, Vtb, Mm, Cc, Cc, 1.0f);

    attn_kernel<<<dim3(Tt / 64, Bb * Hh), 256, 0, stream>>>(Qb, Kbg, Vtb, Ob);

    gemm_bt<0><<<g, 256, 0, stream>>>(Ob, wob, bo, out, Mm, Cc, Cc, 1.0f);
}

// Round 5
// 232.382 us; speedup vs baseline: 2.5389x; 1.1163x over previous
//
#include <hip/hip_runtime.h>
#include <hip/hip_bf16.h>

#define DEVI __device__ __forceinline__

typedef __attribute__((ext_vector_type(4))) float f32x4;
typedef __attribute__((ext_vector_type(8))) short bf16x8;
typedef __attribute__((ext_vector_type(4))) short bf16x4;

constexpr int Bb = 4, Tt = 2048, Cc = 1024, Hh = 16, HDd = 64;
constexpr int Mm = Bb * Tt; // 8192

// ---- bf16 helpers ----
DEVI short f2bf(float f) {
    union { float f; unsigned u; } x; x.f = f;
    unsigned r = x.u + 0x7FFFu + ((x.u >> 16) & 1u); // round-nearest-even
    return (short)(r >> 16);
}

DEVI int cvtpk(float lo, float hi) { // packs {bf16(lo), bf16(hi)}, lo in low 16
    int r;
    asm("v_cvt_pk_bf16_f32 %0, %1, %2" : "=v"(r) : "v"(lo), "v"(hi));
    return r;
}

DEVI void gload_lds16(const void* g, void* l) {
    __builtin_amdgcn_global_load_lds(
        (const __attribute__((address_space(1))) unsigned int*)g,
        (__attribute__((address_space(3))) unsigned int*)l, 16, 0, 0);
}

// ---------------- fp32 -> bf16 conversion ----------------
__global__ void cvt_kernel(const float* __restrict__ s, short* __restrict__ d, int n8) {
    int i = blockIdx.x * 256 + threadIdx.x;
    if (i < n8) {
        const float4* sp = (const float4*)s;
        float4 a = sp[2 * i], b = sp[2 * i + 1];
        short tmp[8];
        tmp[0] = f2bf(a.x); tmp[1] = f2bf(a.y); tmp[2] = f2bf(a.z); tmp[3] = f2bf(a.w);
        tmp[4] = f2bf(b.x); tmp[5] = f2bf(b.y); tmp[6] = f2bf(b.z); tmp[7] = f2bf(b.w);
        *(bf16x8*)(d + 8 * (size_t)i) = *(bf16x8*)tmp;
    }
}

// 4 weight matrices in one launch; blockIdx.y selects.
__global__ void cvtw_kernel(const float* __restrict__ w0, const float* __restrict__ w1,
                            const float* __restrict__ w2, const float* __restrict__ w3,
                            short* __restrict__ d0, short* __restrict__ d1,
                            short* __restrict__ d2, short* __restrict__ d3) {
    const int sel = blockIdx.y;
    const float* s = sel == 0 ? w0 : sel == 1 ? w1 : sel == 2 ? w2 : w3;
    short* d = sel == 0 ? d0 : sel == 1 ? d1 : sel == 2 ? d2 : d3;
    const int i = blockIdx.x * 256 + threadIdx.x;
    const float4* sp = (const float4*)s;
    float4 a = sp[2 * i], b = sp[2 * i + 1];
    short tmp[8];
    tmp[0] = f2bf(a.x); tmp[1] = f2bf(a.y); tmp[2] = f2bf(a.z); tmp[3] = f2bf(a.w);
    tmp[4] = f2bf(b.x); tmp[5] = f2bf(b.y); tmp[6] = f2bf(b.z); tmp[7] = f2bf(b.w);
    *(bf16x8*)(d + 8 * (size_t)i) = *(bf16x8*)tmp;
}

// ---------------- GEMM core (128x128 tile, BK=64) ----------------
struct GemmAcc { f32x4 acc[4][4]; };

DEVI void gemm_core(const short* __restrict__ A, const short* __restrict__ Bw,
                    int Kdim, int bm, int bn, int tid,
                    short (*As)[64], short (*Bs)[64], GemmAcc& G)
{
    const int lane = tid & 63, wid = tid >> 6;
    const int wr = wid >> 1, wc = wid & 1;
    const int lrow = lane >> 3;
    const int lcol = (lane & 7) * 8;

    for (int k0 = 0; k0 < Kdim; k0 += 64) {
        #pragma unroll
        for (int c = 0; c < 4; ++c) {
            const int chunk = wid * 4 + c;
            const int row = chunk * 8 + lrow;
            gload_lds16(A  + (size_t)(bm + row) * Kdim + k0 + lcol, &As[chunk * 8][0]);
            gload_lds16(Bw + (size_t)(bn + row) * Kdim + k0 + lcol, &Bs[chunk * 8][0]);
        }
        __syncthreads();
        const int rr = lane & 15;
        #pragma unroll
        for (int kk = 0; kk < 64; kk += 32) {
            const int koff = kk + (lane >> 4) * 8;
            bf16x8 af[4], bfr[4];
            #pragma unroll
            for (int m_ = 0; m_ < 4; ++m_)
                af[m_] = *(const bf16x8*)&As[wr * 64 + m_ * 16 + rr][koff];
            #pragma unroll
            for (int n_ = 0; n_ < 4; ++n_)
                bfr[n_] = *(const bf16x8*)&Bs[wc * 64 + n_ * 16 + rr][koff];
            #pragma unroll
            for (int m_ = 0; m_ < 4; ++m_)
                #pragma unroll
                for (int n_ = 0; n_ < 4; ++n_)
                    G.acc[m_][n_] = __builtin_amdgcn_mfma_f32_16x16x32_bf16(
                        af[m_], bfr[n_], G.acc[m_][n_], 0, 0, 0);
        }
        __syncthreads();
    }
}

// Fused Q/K/V projection: grid (M/128, 24); blockIdx.y>>3 selects section.
__global__ __launch_bounds__(256, 2)
void gemm_qkv(const short* __restrict__ A,
              const short* __restrict__ Wq, const short* __restrict__ Wk,
              const short* __restrict__ Wv,
              const float* __restrict__ bq, const float* __restrict__ bk,
              const float* __restrict__ bv,
              short* __restrict__ Qo, short* __restrict__ Ko, short* __restrict__ Vto,
              float sq)
{
    __shared__ __align__(16) short As[128][64];
    __shared__ __align__(16) short Bs[128][64];
    const int sec = blockIdx.y >> 3;
    const int bn = (blockIdx.y & 7) * 128;
    const int bm = blockIdx.x * 128;
    const short* Bw = sec == 0 ? Wq : sec == 1 ? Wk : Wv;
    const float* bias = sec == 0 ? bq : sec == 1 ? bk : bv;
    const float scale = sec == 0 ? sq : 1.0f;

    GemmAcc G = {};
    gemm_core(A, Bw, Cc, bm, bn, threadIdx.x, As, Bs, G);

    const int lane = threadIdx.x & 63, wid = threadIdx.x >> 6;
    const int wr = wid >> 1, wc = wid & 1;
    const int cidx = lane & 15;
    const int r4 = (lane >> 4) * 4;
    #pragma unroll
    for (int n_ = 0; n_ < 4; ++n_) {
        const int col = bn + wc * 64 + n_ * 16 + cidx;
        const float bv_ = bias[col];
        #pragma unroll
        for (int m_ = 0; m_ < 4; ++m_) {
            const int rowb = bm + wr * 64 + m_ * 16 + r4;
            if (sec == 2) {
                // transposed V: Vt[((b*16+h)*64 + d)][t]
                const int h_ = col >> 6, d_ = col & 63;
                const int b_ = rowb >> 11, t_ = rowb & 2047;
                short tmp[4];
                #pragma unroll
                for (int i = 0; i < 4; ++i) tmp[i] = f2bf((G.acc[m_][n_][i] + bv_));
                *(bf16x4*)(Vto + ((size_t)((b_ * Hh + h_) * HDd + d_)) * Tt + t_) = *(bf16x4*)tmp;
            } else {
                short* C = sec == 0 ? Qo : Ko;
                #pragma unroll
                for (int i = 0; i < 4; ++i)
                    C[(size_t)(rowb + i) * Cc + col] = f2bf((G.acc[m_][n_][i] + bv_) * scale);
            }
        }
    }
}

// Output projection: fp32 out.
__global__ __launch_bounds__(256, 2)
void gemm_out(const short* __restrict__ A, const short* __restrict__ Bw,
              const float* __restrict__ bias, float* __restrict__ Cout)
{
    __shared__ __align__(16) short As[128][64];
    __shared__ __align__(16) short Bs[128][64];
    const int bm = blockIdx.x * 128;
    const int bn = blockIdx.y * 128;
    GemmAcc G = {};
    gemm_core(A, Bw, Cc, bm, bn, threadIdx.x, As, Bs, G);

    const int lane = threadIdx.x & 63, wid = threadIdx.x >> 6;
    const int wr = wid >> 1, wc = wid & 1;
    const int cidx = lane & 15;
    const int r4 = (lane >> 4) * 4;
    #pragma unroll
    for (int n_ = 0; n_ < 4; ++n_) {
        const int col = bn + wc * 64 + n_ * 16 + cidx;
        const float bv_ = bias[col];
        #pragma unroll
        for (int m_ = 0; m_ < 4; ++m_) {
            const int rowb = bm + wr * 64 + m_ * 16 + r4;
            #pragma unroll
            for (int i = 0; i < 4; ++i)
                Cout[(size_t)(rowb + i) * Cc + col] = G.acc[m_][n_][i] + bv_;
        }
    }
}

// ---------------- Flash attention (causal, counted-vmcnt 2-phase pipeline) ----------------
template<bool DIAG>
DEVI void attn_tile(int kv0, const short (*Kt)[64], const short (*Vd)[64],
                    bf16x8 qf0, bf16x8 qf1, int lane, short (*PsW)[64],
                    f32x4 (&oacc)[4], float &mrow, float &lsum, int qrow)
{
    const int rr = lane & 15;
    const int g  = lane >> 4;

    f32x4 sacc[4] = {};
    __builtin_amdgcn_s_setprio(1);
    #pragma unroll
    for (int n = 0; n < 4; ++n) {
        const int row = n * 16 + rr;
        const int sw = row & 7;
        bf16x8 kf0 = *(const bf16x8*)&Kt[row][((g    ) ^ sw) * 8];
        bf16x8 kf1 = *(const bf16x8*)&Kt[row][((g + 4) ^ sw) * 8];
        sacc[n] = __builtin_amdgcn_mfma_f32_16x16x32_bf16(kf0, qf0, sacc[n], 0, 0, 0);
        sacc[n] = __builtin_amdgcn_mfma_f32_16x16x32_bf16(kf1, qf1, sacc[n], 0, 0, 0);
    }
    __builtin_amdgcn_s_setprio(0);

    // lane holds S[kv0 + n*16 + g*4 + i][qrow]; scale folded into Q
    float p[4][4];
    float pmax = -1e30f;
    #pragma unroll
    for (int n = 0; n < 4; ++n)
        #pragma unroll
        for (int i = 0; i < 4; ++i) {
            float s = sacc[n][i];
            if (DIAG) { if (kv0 + n * 16 + g * 4 + i > qrow) s = -1e30f; }
            p[n][i] = s;
            pmax = fmaxf(pmax, s);
        }
    pmax = fmaxf(pmax, __shfl_xor(pmax, 16, 64));
    pmax = fmaxf(pmax, __shfl_xor(pmax, 32, 64));

    if (!__all(pmax <= mrow + 8.0f)) {          // defer-max: rescale rarely
        const float mnew = fmaxf(mrow, pmax);
        const float alpha = exp2f(mrow - mnew);
        mrow = mnew;
        lsum *= alpha;
        float alphaq[4];
        #pragma unroll
        for (int i = 0; i < 4; ++i) alphaq[i] = __shfl(alpha, g * 4 + i, 16);
        #pragma unroll
        for (int n = 0; n < 4; ++n)
            #pragma unroll
            for (int i = 0; i < 4; ++i) oacc[n][i] *= alphaq[i];
    }

    // exp2, per-lane partial sum, pack to bf16, swizzled b64 stores to Ps[q][kv]
    #pragma unroll
    for (int n = 0; n < 4; ++n) {
        #pragma unroll
        for (int i = 0; i < 4; ++i) {
            p[n][i] = exp2f(p[n][i] - mrow);
            lsum += p[n][i];
        }
        const unsigned u0 = (unsigned)cvtpk(p[n][0], p[n][1]);
        const unsigned u1 = (unsigned)cvtpk(p[n][2], p[n][3]);
        const int chunk = (2 * n + (g >> 1)) ^ (rr & 7);
        *(unsigned long long*)&PsW[rr][chunk * 8 + (g & 1) * 4] =
            ((unsigned long long)u1 << 32) | u0;
    }

    // PV: pf = P[q=rr][ks*32 + g*8 .. +7] (same swizzle), vf from transposed V tile
    #pragma unroll
    for (int ks = 0; ks < 2; ++ks) {
        const int rchunk = (4 * ks + g) ^ (rr & 7);
        bf16x8 pf = *(const bf16x8*)&PsW[rr][rchunk * 8];
        __builtin_amdgcn_s_setprio(1);
        #pragma unroll
        for (int n = 0; n < 4; ++n) {
            const int row = n * 16 + rr;
            const int sw = row & 7;
            bf16x8 vf = *(const bf16x8*)&Vd[row][((ks * 4 + g) ^ sw) * 8];
            oacc[n] = __builtin_amdgcn_mfma_f32_16x16x32_bf16(pf, vf, oacc[n], 0, 0, 0);
        }
        __builtin_amdgcn_s_setprio(0);
    }
}

__global__ __launch_bounds__(256, 4)
void attn_kernel(const short* __restrict__ Q, const short* __restrict__ K,
                 const short* __restrict__ Vt, short* __restrict__ O)
{
    const int qt = gridDim.x - 1 - blockIdx.x;   // longest blocks first
    const int bh = blockIdx.y;
    const int b = bh >> 4, h = bh & 15;
    const size_t baseRow = (size_t)b * Tt;
    const int q0 = qt * 64;
    const int tid = threadIdx.x, lane = tid & 63, wid = tid >> 6;
    const int rr = lane & 15;
    const int g = lane >> 4;

    __shared__ __align__(16) short Kb[2][64][64];
    __shared__ __align__(16) short Vb[2][64][64];
    __shared__ __align__(16) short Ps[4][16][64];
    short (*PsW)[64] = Ps[wid];

    const int qrow = q0 + wid * 16 + rr;
    const short* qptr = Q + (baseRow + qrow) * Cc + h * HDd + g * 8;
    bf16x8 qf0 = *(const bf16x8*)qptr;
    bf16x8 qf1 = *(const bf16x8*)(qptr + 32);

    const short* kbase = K + baseRow * Cc + h * HDd;
    const short* vbase = Vt + (size_t)bh * HDd * Tt;

    f32x4 oacc[4] = {};
    float mrow = -1e30f, lsum = 0.f;
    const int nkv = qt + 1;

    auto STAGE = [&](int bsel, int kv0) {
        #pragma unroll
        for (int j = 0; j < 2; ++j) {
            const int r0 = wid * 16 + j * 8;
            const int row = r0 + (lane >> 3);
            const int sc = ((lane & 7) ^ (row & 7)) * 8;   // source-side chunk swizzle
            gload_lds16(kbase + (size_t)(kv0 + row) * Cc + sc, &Kb[bsel][r0][0]);
            gload_lds16(vbase + (size_t)row * Tt + kv0 + sc, &Vb[bsel][r0][0]);
        }
    };

    // 2-phase counted-vmcnt pipeline: next tile's 4 loads stay in flight across
    // the barrier (never drained to 0 in the main loop) — T3+T4.
    STAGE(0, 0);
    int buf = 0;
    for (int kt = 0; kt < nkv; ++kt) {
        if (kt + 1 < nkv) {
            STAGE(buf ^ 1, (kt + 1) * 64);                 // +4 in flight (8 total)
            asm volatile("s_waitcnt vmcnt(4)" ::: "memory"); // current tile landed
        } else {
            asm volatile("s_waitcnt vmcnt(0)" ::: "memory");
        }
        __builtin_amdgcn_s_barrier();        // all waves' current-tile loads landed
        __builtin_amdgcn_sched_barrier(0);
        if (kt == nkv - 1)
            attn_tile<true >(kt * 64, Kb[buf], Vb[buf], qf0, qf1, lane, PsW, oacc, mrow, lsum, qrow);
        else
            attn_tile<false>(kt * 64, Kb[buf], Vb[buf], qf0, qf1, lane, PsW, oacc, mrow, lsum, qrow);
        __builtin_amdgcn_s_barrier();        // safe to overwrite buf next iter
        buf ^= 1;
    }

    // epilogue: total l per q-row (2-step cross-group reduce), fetch per-row totals
    lsum += __shfl_xor(lsum, 16, 64);
    lsum += __shfl_xor(lsum, 32, 64);
    float rinv[4];
    #pragma unroll
    for (int i = 0; i < 4; ++i)
        rinv[i] = 1.0f / __shfl(lsum, g * 4 + i, 16);

    #pragma unroll
    for (int n = 0; n < 4; ++n)
        #pragma unroll
        for (int i = 0; i < 4; ++i)
            O[(baseRow + q0 + wid * 16 + g * 4 + i) * Cc + h * HDd + n * 16 + rr] =
                f2bf(oacc[n][i] * rinv[i]);
}

// ---------------- host ----------------
extern "C" void kernel_launch(void* const* d_in, const int* in_sizes, int n_in,
                              void* d_out, int out_size, void* d_ws, size_t ws_size,
                              hipStream_t stream) {
    (void)in_sizes; (void)n_in; (void)out_size; (void)ws_size;
    const float* x  = (const float*)d_in[0];
    const float* Wq = (const float*)d_in[1];
    const float* bq = (const float*)d_in[2];
    const float* Wk = (const float*)d_in[3];
    const float* bk = (const float*)d_in[4];
    const float* Wv = (const float*)d_in[5];
    const float* bv = (const float*)d_in[6];
    const float* Wo = (const float*)d_in[7];
    const float* bo = (const float*)d_in[8];
    float* out = (float*)d_out;

    short* ws  = (short*)d_ws;
    short* xb  = ws;
    short* wqb = xb  + (size_t)Mm * Cc;
    short* wkb = wqb + (size_t)Cc * Cc;
    short* wvb = wkb + (size_t)Cc * Cc;
    short* wob = wvb + (size_t)Cc * Cc;
    short* Qb  = wob + (size_t)Cc * Cc;
    short* Kbg = Qb  + (size_t)Mm * Cc;
    short* Vtb = Kbg + (size_t)Mm * Cc;  // V written pre-transposed by the QKV GEMM
    short* Ob  = Vtb + (size_t)Mm * Cc;

    const int nx8 = Mm * Cc / 8;
    const int nw8 = Cc * Cc / 8;
    cvt_kernel<<<(nx8 + 255) / 256, 256, 0, stream>>>(x, xb, nx8);
    cvtw_kernel<<<dim3(nw8 / 256, 4), 256, 0, stream>>>(Wq, Wk, Wv, Wo, wqb, wkb, wvb, wob);

    const float SCL = 0.125f * 1.44269504088896f;  // 1/sqrt(HD) * log2(e), folded into Q
    gemm_qkv<<<dim3(Mm / 128, 24), 256, 0, stream>>>(xb, wqb, wkb, wvb, bq, bk, bv,
                                                     Qb, Kbg, Vtb, SCL);

    attn_kernel<<<dim3(Tt / 64, Bb * Hh), 256, 0, stream>>>(Qb, Kbg, Vtb, Ob);

    gemm_out<<<dim3(Mm / 128, Cc / 128), 256, 0, stream>>>(Ob, wob, bo, out);
}

// Round 6
// 186.994 us; speedup vs baseline: 3.1552x; 1.2427x over previous
//
#include <hip/hip_runtime.h>
#include <hip/hip_bf16.h>

#define DEVI __device__ __forceinline__

typedef __attribute__((ext_vector_type(4))) float f32x4;
typedef __attribute__((ext_vector_type(8))) short bf16x8;
typedef __attribute__((ext_vector_type(4))) short bf16x4;

constexpr int Bb = 4, Tt = 2048, Cc = 1024, Hh = 16, HDd = 64;
constexpr int Mm = Bb * Tt; // 8192

// ---- bf16 helpers ----
DEVI short f2bf(float f) {
    union { float f; unsigned u; } x; x.f = f;
    unsigned r = x.u + 0x7FFFu + ((x.u >> 16) & 1u); // round-nearest-even
    return (short)(r >> 16);
}

DEVI int cvtpk(float lo, float hi) { // packs {bf16(lo), bf16(hi)}, lo in low 16
    int r;
    asm("v_cvt_pk_bf16_f32 %0, %1, %2" : "=v"(r) : "v"(lo), "v"(hi));
    return r;
}

DEVI void gload_lds16(const void* g, void* l) {
    __builtin_amdgcn_global_load_lds(
        (const __attribute__((address_space(1))) unsigned int*)g,
        (__attribute__((address_space(3))) unsigned int*)l, 16, 0, 0);
}

// ---------------- fp32 -> bf16 conversion ----------------
__global__ void cvt_kernel(const float* __restrict__ s, short* __restrict__ d, int n8) {
    int i = blockIdx.x * 256 + threadIdx.x;
    if (i < n8) {
        const float4* sp = (const float4*)s;
        float4 a = sp[2 * i], b = sp[2 * i + 1];
        short tmp[8];
        tmp[0] = f2bf(a.x); tmp[1] = f2bf(a.y); tmp[2] = f2bf(a.z); tmp[3] = f2bf(a.w);
        tmp[4] = f2bf(b.x); tmp[5] = f2bf(b.y); tmp[6] = f2bf(b.z); tmp[7] = f2bf(b.w);
        *(bf16x8*)(d + 8 * (size_t)i) = *(bf16x8*)tmp;
    }
}

// 4 weight matrices in one launch; blockIdx.y selects.
__global__ void cvtw_kernel(const float* __restrict__ w0, const float* __restrict__ w1,
                            const float* __restrict__ w2, const float* __restrict__ w3,
                            short* __restrict__ d0, short* __restrict__ d1,
                            short* __restrict__ d2, short* __restrict__ d3) {
    const int sel = blockIdx.y;
    const float* s = sel == 0 ? w0 : sel == 1 ? w1 : sel == 2 ? w2 : w3;
    short* d = sel == 0 ? d0 : sel == 1 ? d1 : sel == 2 ? d2 : d3;
    const int i = blockIdx.x * 256 + threadIdx.x;
    const float4* sp = (const float4*)s;
    float4 a = sp[2 * i], b = sp[2 * i + 1];
    short tmp[8];
    tmp[0] = f2bf(a.x); tmp[1] = f2bf(a.y); tmp[2] = f2bf(a.z); tmp[3] = f2bf(a.w);
    tmp[4] = f2bf(b.x); tmp[5] = f2bf(b.y); tmp[6] = f2bf(b.z); tmp[7] = f2bf(b.w);
    *(bf16x8*)(d + 8 * (size_t)i) = *(bf16x8*)tmp;
}

// ---------------- GEMM core (128x128 tile, BK=64) ----------------
struct GemmAcc { f32x4 acc[4][4]; };

DEVI void gemm_core(const short* __restrict__ A, const short* __restrict__ Bw,
                    int Kdim, int bm, int bn, int tid,
                    short (*As)[64], short (*Bs)[64], GemmAcc& G)
{
    const int lane = tid & 63, wid = tid >> 6;
    const int wr = wid >> 1, wc = wid & 1;
    const int lrow = lane >> 3;
    const int lcol = (lane & 7) * 8;

    for (int k0 = 0; k0 < Kdim; k0 += 64) {
        #pragma unroll
        for (int c = 0; c < 4; ++c) {
            const int chunk = wid * 4 + c;
            const int row = chunk * 8 + lrow;
            gload_lds16(A  + (size_t)(bm + row) * Kdim + k0 + lcol, &As[chunk * 8][0]);
            gload_lds16(Bw + (size_t)(bn + row) * Kdim + k0 + lcol, &Bs[chunk * 8][0]);
        }
        __syncthreads();
        const int rr = lane & 15;
        #pragma unroll
        for (int kk = 0; kk < 64; kk += 32) {
            const int koff = kk + (lane >> 4) * 8;
            bf16x8 af[4], bfr[4];
            #pragma unroll
            for (int m_ = 0; m_ < 4; ++m_)
                af[m_] = *(const bf16x8*)&As[wr * 64 + m_ * 16 + rr][koff];
            #pragma unroll
            for (int n_ = 0; n_ < 4; ++n_)
                bfr[n_] = *(const bf16x8*)&Bs[wc * 64 + n_ * 16 + rr][koff];
            #pragma unroll
            for (int m_ = 0; m_ < 4; ++m_)
                #pragma unroll
                for (int n_ = 0; n_ < 4; ++n_)
                    G.acc[m_][n_] = __builtin_amdgcn_mfma_f32_16x16x32_bf16(
                        af[m_], bfr[n_], G.acc[m_][n_], 0, 0, 0);
        }
        __syncthreads();
    }
}

// Fused Q/K/V projection: grid (M/128, 24); blockIdx.y>>3 selects section.
__global__ __launch_bounds__(256, 2)
void gemm_qkv(const short* __restrict__ A,
              const short* __restrict__ Wq, const short* __restrict__ Wk,
              const short* __restrict__ Wv,
              const float* __restrict__ bq, const float* __restrict__ bk,
              const float* __restrict__ bv,
              short* __restrict__ Qo, short* __restrict__ Ko, short* __restrict__ Vto,
              float sq)
{
    __shared__ __align__(16) short As[128][64];
    __shared__ __align__(16) short Bs[128][64];
    const int sec = blockIdx.y >> 3;
    const int bn = (blockIdx.y & 7) * 128;
    const int bm = blockIdx.x * 128;
    const short* Bw = sec == 0 ? Wq : sec == 1 ? Wk : Wv;
    const float* bias = sec == 0 ? bq : sec == 1 ? bk : bv;
    const float scale = sec == 0 ? sq : 1.0f;

    GemmAcc G = {};
    gemm_core(A, Bw, Cc, bm, bn, threadIdx.x, As, Bs, G);

    const int lane = threadIdx.x & 63, wid = threadIdx.x >> 6;
    const int wr = wid >> 1, wc = wid & 1;
    const int cidx = lane & 15;
    const int r4 = (lane >> 4) * 4;
    #pragma unroll
    for (int n_ = 0; n_ < 4; ++n_) {
        const int col = bn + wc * 64 + n_ * 16 + cidx;
        const float bv_ = bias[col];
        #pragma unroll
        for (int m_ = 0; m_ < 4; ++m_) {
            const int rowb = bm + wr * 64 + m_ * 16 + r4;
            if (sec == 2) {
                // transposed V: Vt[((b*16+h)*64 + d)][t]
                const int h_ = col >> 6, d_ = col & 63;
                const int b_ = rowb >> 11, t_ = rowb & 2047;
                short tmp[4];
                #pragma unroll
                for (int i = 0; i < 4; ++i) tmp[i] = f2bf((G.acc[m_][n_][i] + bv_));
                *(bf16x4*)(Vto + ((size_t)((b_ * Hh + h_) * HDd + d_)) * Tt + t_) = *(bf16x4*)tmp;
            } else {
                short* C = sec == 0 ? Qo : Ko;
                #pragma unroll
                for (int i = 0; i < 4; ++i)
                    C[(size_t)(rowb + i) * Cc + col] = f2bf((G.acc[m_][n_][i] + bv_) * scale);
            }
        }
    }
}

// Output projection: fp32 out.
__global__ __launch_bounds__(256, 2)
void gemm_out(const short* __restrict__ A, const short* __restrict__ Bw,
              const float* __restrict__ bias, float* __restrict__ Cout)
{
    __shared__ __align__(16) short As[128][64];
    __shared__ __align__(16) short Bs[128][64];
    const int bm = blockIdx.x * 128;
    const int bn = blockIdx.y * 128;
    GemmAcc G = {};
    gemm_core(A, Bw, Cc, bm, bn, threadIdx.x, As, Bs, G);

    const int lane = threadIdx.x & 63, wid = threadIdx.x >> 6;
    const int wr = wid >> 1, wc = wid & 1;
    const int cidx = lane & 15;
    const int r4 = (lane >> 4) * 4;
    #pragma unroll
    for (int n_ = 0; n_ < 4; ++n_) {
        const int col = bn + wc * 64 + n_ * 16 + cidx;
        const float bv_ = bias[col];
        #pragma unroll
        for (int m_ = 0; m_ < 4; ++m_) {
            const int rowb = bm + wr * 64 + m_ * 16 + r4;
            #pragma unroll
            for (int i = 0; i < 4; ++i)
                Cout[(size_t)(rowb + i) * Cc + col] = G.acc[m_][n_][i] + bv_;
        }
    }
}

// ---------------- Flash attention (causal, paired q-tiles for load balance) ----------------
template<bool DIAG>
DEVI void attn_tile(int kv0, const short (*Kt)[64], const short (*Vd)[64],
                    bf16x8 qf0, bf16x8 qf1, int lane, short (*PsW)[64],
                    f32x4 (&oacc)[4], float &mrow, float &lsum, int qrow)
{
    const int rr = lane & 15;
    const int g  = lane >> 4;

    f32x4 sacc[4] = {};
    __builtin_amdgcn_s_setprio(1);
    #pragma unroll
    for (int n = 0; n < 4; ++n) {
        const int row = n * 16 + rr;
        const int sw = row & 7;
        bf16x8 kf0 = *(const bf16x8*)&Kt[row][((g    ) ^ sw) * 8];
        bf16x8 kf1 = *(const bf16x8*)&Kt[row][((g + 4) ^ sw) * 8];
        sacc[n] = __builtin_amdgcn_mfma_f32_16x16x32_bf16(kf0, qf0, sacc[n], 0, 0, 0);
        sacc[n] = __builtin_amdgcn_mfma_f32_16x16x32_bf16(kf1, qf1, sacc[n], 0, 0, 0);
    }
    __builtin_amdgcn_s_setprio(0);

    // lane holds S[kv0 + n*16 + g*4 + i][qrow]; scale folded into Q
    float p[4][4];
    float pmax = -1e30f;
    #pragma unroll
    for (int n = 0; n < 4; ++n)
        #pragma unroll
        for (int i = 0; i < 4; ++i) {
            float s = sacc[n][i];
            if (DIAG) { if (kv0 + n * 16 + g * 4 + i > qrow) s = -1e30f; }
            p[n][i] = s;
            pmax = fmaxf(pmax, s);
        }
    pmax = fmaxf(pmax, __shfl_xor(pmax, 16, 64));
    pmax = fmaxf(pmax, __shfl_xor(pmax, 32, 64));

    if (!__all(pmax <= mrow + 8.0f)) {          // defer-max: rescale rarely
        const float mnew = fmaxf(mrow, pmax);
        const float alpha = exp2f(mrow - mnew);
        mrow = mnew;
        lsum *= alpha;
        float alphaq[4];
        #pragma unroll
        for (int i = 0; i < 4; ++i) alphaq[i] = __shfl(alpha, g * 4 + i, 16);
        #pragma unroll
        for (int n = 0; n < 4; ++n)
            #pragma unroll
            for (int i = 0; i < 4; ++i) oacc[n][i] *= alphaq[i];
    }

    // exp2, per-lane partial sum, pack to bf16, swizzled b64 stores to Ps[q][kv]
    #pragma unroll
    for (int n = 0; n < 4; ++n) {
        #pragma unroll
        for (int i = 0; i < 4; ++i) {
            p[n][i] = exp2f(p[n][i] - mrow);
            lsum += p[n][i];
        }
        const unsigned u0 = (unsigned)cvtpk(p[n][0], p[n][1]);
        const unsigned u1 = (unsigned)cvtpk(p[n][2], p[n][3]);
        const int chunk = (2 * n + (g >> 1)) ^ (rr & 7);
        *(unsigned long long*)&PsW[rr][chunk * 8 + (g & 1) * 4] =
            ((unsigned long long)u1 << 32) | u0;
    }

    // PV: pf = P[q=rr][ks*32 + g*8 .. +7] (same swizzle), vf from transposed V tile
    #pragma unroll
    for (int ks = 0; ks < 2; ++ks) {
        const int rchunk = (4 * ks + g) ^ (rr & 7);
        bf16x8 pf = *(const bf16x8*)&PsW[rr][rchunk * 8];
        __builtin_amdgcn_s_setprio(1);
        #pragma unroll
        for (int n = 0; n < 4; ++n) {
            const int row = n * 16 + rr;
            const int sw = row & 7;
            bf16x8 vf = *(const bf16x8*)&Vd[row][((ks * 4 + g) ^ sw) * 8];
            oacc[n] = __builtin_amdgcn_mfma_f32_16x16x32_bf16(pf, vf, oacc[n], 0, 0, 0);
        }
        __builtin_amdgcn_s_setprio(0);
    }
}

// One full q-tile pass (staging pipeline + online softmax + epilogue).
DEVI void attn_run(int qt, const short* __restrict__ Q, short* __restrict__ O,
                   const short* kbase, const short* vbase, size_t baseRow, int h,
                   int lane, int wid,
                   short (*Kb)[64][64], short (*Vb)[64][64], short (*PsW)[64])
{
    const int q0 = qt * 64;
    const int rr = lane & 15;
    const int g = lane >> 4;

    const int qrow = q0 + wid * 16 + rr;
    const short* qptr = Q + (baseRow + qrow) * Cc + h * HDd + g * 8;
    bf16x8 qf0 = *(const bf16x8*)qptr;
    bf16x8 qf1 = *(const bf16x8*)(qptr + 32);

    f32x4 oacc[4] = {};
    float mrow = -1e30f, lsum = 0.f;
    const int nkv = qt + 1;

    auto STAGE = [&](int bsel, int kv0) {
        #pragma unroll
        for (int j = 0; j < 2; ++j) {
            const int r0 = wid * 16 + j * 8;
            const int row = r0 + (lane >> 3);
            const int sc = ((lane & 7) ^ (row & 7)) * 8;   // source-side chunk swizzle
            gload_lds16(kbase + (size_t)(kv0 + row) * Cc + sc, &Kb[bsel][r0][0]);
            gload_lds16(vbase + (size_t)row * Tt + kv0 + sc, &Vb[bsel][r0][0]);
        }
    };

    // 2-phase counted-vmcnt pipeline: next tile's loads stay in flight across
    // the barrier (never drained to 0 in the main loop).
    STAGE(0, 0);
    int buf = 0;
    for (int kt = 0; kt < nkv; ++kt) {
        if (kt + 1 < nkv) {
            STAGE(buf ^ 1, (kt + 1) * 64);                   // +4 in flight (8 total)
            asm volatile("s_waitcnt vmcnt(4)" ::: "memory"); // current tile landed
        } else {
            asm volatile("s_waitcnt vmcnt(0)" ::: "memory");
        }
        __builtin_amdgcn_s_barrier();        // all waves' current-tile loads landed
        __builtin_amdgcn_sched_barrier(0);
        if (kt == nkv - 1)
            attn_tile<true >(kt * 64, Kb[buf], Vb[buf], qf0, qf1, lane, PsW, oacc, mrow, lsum, qrow);
        else
            attn_tile<false>(kt * 64, Kb[buf], Vb[buf], qf0, qf1, lane, PsW, oacc, mrow, lsum, qrow);
        __builtin_amdgcn_s_barrier();        // safe to overwrite buf next iter / next phase
        buf ^= 1;
    }

    // epilogue: total l per q-row (2-step cross-group reduce), fetch per-row totals
    lsum += __shfl_xor(lsum, 16, 64);
    lsum += __shfl_xor(lsum, 32, 64);
    float rinv[4];
    #pragma unroll
    for (int i = 0; i < 4; ++i)
        rinv[i] = 1.0f / __shfl(lsum, g * 4 + i, 16);

    #pragma unroll
    for (int n = 0; n < 4; ++n)
        #pragma unroll
        for (int i = 0; i < 4; ++i)
            O[(baseRow + q0 + wid * 16 + g * 4 + i) * Cc + h * HDd + n * 16 + rr] =
                f2bf(oacc[n][i] * rinv[i]);
}

// grid (16, 64): block handles q-tiles {j, 31-j} -> 33 KV-tiles for EVERY block
// (perfect causal load balance; 1024 blocks = 4/CU all resident, no tail).
__global__ __launch_bounds__(256, 4)
void attn_kernel(const short* __restrict__ Q, const short* __restrict__ K,
                 const short* __restrict__ Vt, short* __restrict__ O)
{
    const int bh = blockIdx.y;
    const int b = bh >> 4, h = bh & 15;
    const size_t baseRow = (size_t)b * Tt;
    const int tid = threadIdx.x, lane = tid & 63, wid = tid >> 6;

    __shared__ __align__(16) short Kb[2][64][64];
    __shared__ __align__(16) short Vb[2][64][64];
    __shared__ __align__(16) short Ps[4][16][64];
    short (*PsW)[64] = Ps[wid];

    const short* kbase = K + baseRow * Cc + h * HDd;
    const short* vbase = Vt + (size_t)bh * HDd * Tt;

    const int qtA = blockIdx.x;                 // short phase (qtA+1 tiles)
    const int qtB = (Tt / 64 - 1) - blockIdx.x; // long phase (32-qtA tiles)

    attn_run(qtB, Q, O, kbase, vbase, baseRow, h, lane, wid, Kb, Vb, PsW);
    attn_run(qtA, Q, O, kbase, vbase, baseRow, h, lane, wid, Kb, Vb, PsW);
}

// ---------------- host ----------------
extern "C" void kernel_launch(void* const* d_in, const int* in_sizes, int n_in,
                              void* d_out, int out_size, void* d_ws, size_t ws_size,
                              hipStream_t stream) {
    (void)in_sizes; (void)n_in; (void)out_size; (void)ws_size;
    const float* x  = (const float*)d_in[0];
    const float* Wq = (const float*)d_in[1];
    const float* bq = (const float*)d_in[2];
    const float* Wk = (const float*)d_in[3];
    const float* bk = (const float*)d_in[4];
    const float* Wv = (const float*)d_in[5];
    const float* bv = (const float*)d_in[6];
    const float* Wo = (const float*)d_in[7];
    const float* bo = (const float*)d_in[8];
    float* out = (float*)d_out;

    short* ws  = (short*)d_ws;
    short* xb  = ws;
    short* wqb = xb  + (size_t)Mm * Cc;
    short* wkb = wqb + (size_t)Cc * Cc;
    short* wvb = wkb + (size_t)Cc * Cc;
    short* wob = wvb + (size_t)Cc * Cc;
    short* Qb  = wob + (size_t)Cc * Cc;
    short* Kbg = Qb  + (size_t)Mm * Cc;
    short* Vtb = Kbg + (size_t)Mm * Cc;  // V written pre-transposed by the QKV GEMM
    short* Ob  = Vtb + (size_t)Mm * Cc;

    const int nx8 = Mm * Cc / 8;
    const int nw8 = Cc * Cc / 8;
    cvt_kernel<<<(nx8 + 255) / 256, 256, 0, stream>>>(x, xb, nx8);
    cvtw_kernel<<<dim3(nw8 / 256, 4), 256, 0, stream>>>(Wq, Wk, Wv, Wo, wqb, wkb, wvb, wob);

    const float SCL = 0.125f * 1.44269504088896f;  // 1/sqrt(HD) * log2(e), folded into Q
    gemm_qkv<<<dim3(Mm / 128, 24), 256, 0, stream>>>(xb, wqb, wkb, wvb, bq, bk, bv,
                                                     Qb, Kbg, Vtb, SCL);

    attn_kernel<<<dim3(Tt / 128, Bb * Hh), 256, 0, stream>>>(Qb, Kbg, Vtb, Ob);

    gemm_out<<<dim3(Mm / 128, Cc / 128), 256, 0, stream>>>(Ob, wob, bo, out);
}